// Round 2
// baseline (248.674 us; speedup 1.0000x reference)
//
#include <hip/hip_runtime.h>

// InputDefenseLayer: clip(x, -3.5, 3.5) then EMA scan along T (axis 1):
//   s_0 = xc_0 ; s_t = 0.25*xc_t + 0.75*s_{t-1}
// x: (B=64, T=2048, C=256) float32, contiguous, C innermost.
//
// R3 changes vs R2 (R2: 84 us, 3.0 TB/s -- same plateau as R1 despite 4x
// different bytes-in-flight => NOT an MLP limit):
//  - THEORY: in-order vmcnt retire means consuming load(r) also waits for
//    store(r-8), which was issued right before it. Every row's wait chain
//    therefore includes a non-temporal store ACK (~HBM write RTT). This
//    coupling is identical in R0/R1/R2 -> explains the 3-kernel plateau,
//    while write-only fill hits 6.7 TB/s on the same device.
//  - FIX: buffer 16 output rows in NAMED registers o0..o15 (static indices
//    only -- rule: runtime-indexed arrays spill to scratch) and store them
//    in two back-to-back 16-store bursts per job. EMA groups now have a
//    loads-only vmcnt stream (copy-like); store acks can gate a load wait
//    only once per 16 rows instead of every row.
//  - Depth-8 load prefetch (p0..p7) kept; float4 lanes kept (1 wave/job,
//    4096 jobs); __launch_bounds__(256,4) keeps the 128-VGPR budget for
//    p(32) + o(64) + state/addr (~16).
// Numerics identical to R1/R2: seed at t0-W, W=24 -> err 7*0.75^24 ~ 7e-3.

constexpr int B = 64;
constexpr int T = 2048;
constexpr int C = 256;
constexpr int L = 32;            // output chunk length along T
constexpr int W = 24;            // warm-up steps: 7*0.75^24 ~ 7e-3 < 7e-2
constexpr int NCHUNK = T / L;    // 64
constexpr int ROWF4 = C / 4;     // 64 float4 per t-row
constexpr int PF = 8;            // load prefetch depth

#define CLIP_LO -3.5f
#define CLIP_HI  3.5f
#define EMA_A 0.25f
#define EMA_B 0.75f

typedef float f4 __attribute__((ext_vector_type(4)));

__device__ __forceinline__ float clipf(float v) {
    return fminf(fmaxf(v, CLIP_LO), CLIP_HI);   // -> v_med3_f32
}

__device__ __forceinline__ f4 clip4(f4 v) {
    f4 r;
    r.x = clipf(v.x);
    r.y = clipf(v.y);
    r.z = clipf(v.z);
    r.w = clipf(v.w);
    return r;
}

__device__ __forceinline__ f4 ema4(f4 s, f4 v) {
    f4 r;
    r.x = fmaf(EMA_A, v.x, EMA_B * s.x);
    r.y = fmaf(EMA_A, v.y, EMA_B * s.y);
    r.z = fmaf(EMA_A, v.z, EMA_B * s.z);
    r.w = fmaf(EMA_A, v.w, EMA_B * s.w);
    return r;
}

// Consume row r from prefetch register p##j; re-issue load for row r+PF.
// No store (warm-up). All guards fold at compile time (r, N are constants).
#define STEP(j, r)                                                   \
    {                                                                \
        f4 v = clip4(p##j);                                          \
        s = ((r) == 0) ? v : ema4(s, v);                             \
        if ((r) + PF < N) p##j = xp[((r) + PF) * ROWF4];             \
    }

// Same, but also latch the state into output register oo (named, static).
#define OSTEP(j, r, oo)                                              \
    {                                                                \
        f4 v = clip4(p##j);                                          \
        s = ((r) == 0) ? v : ema4(s, v);                             \
        oo = s;                                                      \
        if ((r) + PF < N) p##j = xp[((r) + PF) * ROWF4];             \
    }

// 8 warm-up rows starting at compile-time row r0.
#define G8W(r0)                                                      \
    STEP(0, (r0) + 0) STEP(1, (r0) + 1) STEP(2, (r0) + 2)            \
    STEP(3, (r0) + 3) STEP(4, (r0) + 4) STEP(5, (r0) + 5)            \
    STEP(6, (r0) + 6) STEP(7, (r0) + 7)

// 16 output rows starting at r0, latched into o0..o15 (no stores here --
// the vmcnt stream in this region is loads-only).
#define G16S(r0)                                                     \
    OSTEP(0, (r0) + 0,  o0)  OSTEP(1, (r0) + 1,  o1)                 \
    OSTEP(2, (r0) + 2,  o2)  OSTEP(3, (r0) + 3,  o3)                 \
    OSTEP(4, (r0) + 4,  o4)  OSTEP(5, (r0) + 5,  o5)                 \
    OSTEP(6, (r0) + 6,  o6)  OSTEP(7, (r0) + 7,  o7)                 \
    OSTEP(0, (r0) + 8,  o8)  OSTEP(1, (r0) + 9,  o9)                 \
    OSTEP(2, (r0) + 10, o10) OSTEP(3, (r0) + 11, o11)                \
    OSTEP(4, (r0) + 12, o12) OSTEP(5, (r0) + 13, o13)                \
    OSTEP(6, (r0) + 14, o14) OSTEP(7, (r0) + 15, o15)

// Burst-store 16 buffered rows, back-to-back, ascending addresses.
#define BURST(r0)                                                    \
    __builtin_nontemporal_store(o0,  op + ((r0) + 0)  * ROWF4);      \
    __builtin_nontemporal_store(o1,  op + ((r0) + 1)  * ROWF4);      \
    __builtin_nontemporal_store(o2,  op + ((r0) + 2)  * ROWF4);      \
    __builtin_nontemporal_store(o3,  op + ((r0) + 3)  * ROWF4);      \
    __builtin_nontemporal_store(o4,  op + ((r0) + 4)  * ROWF4);      \
    __builtin_nontemporal_store(o5,  op + ((r0) + 5)  * ROWF4);      \
    __builtin_nontemporal_store(o6,  op + ((r0) + 6)  * ROWF4);      \
    __builtin_nontemporal_store(o7,  op + ((r0) + 7)  * ROWF4);      \
    __builtin_nontemporal_store(o8,  op + ((r0) + 8)  * ROWF4);      \
    __builtin_nontemporal_store(o9,  op + ((r0) + 9)  * ROWF4);      \
    __builtin_nontemporal_store(o10, op + ((r0) + 10) * ROWF4);      \
    __builtin_nontemporal_store(o11, op + ((r0) + 11) * ROWF4);      \
    __builtin_nontemporal_store(o12, op + ((r0) + 12) * ROWF4);      \
    __builtin_nontemporal_store(o13, op + ((r0) + 13) * ROWF4);      \
    __builtin_nontemporal_store(o14, op + ((r0) + 14) * ROWF4);      \
    __builtin_nontemporal_store(o15, op + ((r0) + 15) * ROWF4);

// Process rows [0, N): row 0 seeds the EMA state, rows >= SKIP are stored.
// SKIP is 0 (k==0 chunk) or W=24 (warm-up) -- both handled with static
// group sequences so every register index is compile-time.
template <int N, int SKIP>
__device__ __forceinline__ void run_rows(const f4* __restrict__ xp,
                                         f4* __restrict__ op) {
    f4 p0 = xp[0 * ROWF4];
    f4 p1 = xp[1 * ROWF4];
    f4 p2 = xp[2 * ROWF4];
    f4 p3 = xp[3 * ROWF4];
    f4 p4 = xp[4 * ROWF4];
    f4 p5 = xp[5 * ROWF4];
    f4 p6 = xp[6 * ROWF4];
    f4 p7 = xp[7 * ROWF4];
    f4 s = {};
    f4 o0, o1, o2, o3, o4, o5, o6, o7, o8, o9, o10, o11, o12, o13, o14, o15;

    if constexpr (SKIP == 0) {
        static_assert(N == L, "k==0 path is 32 rows");
        G16S(0)
        BURST(0)
        G16S(16)
        BURST(16)
    } else {
        static_assert(SKIP == W && N == W + L, "warm-up path is 24+32 rows");
        G8W(0)
        G8W(8)
        G8W(16)
        G16S(W)
        BURST(W)
        G16S(W + 16)
        BURST(W + 16)
    }
}

__global__ __launch_bounds__(256, 4) void ema_kernel(
    const float* __restrict__ x, float* __restrict__ out)
{
    // 4 chunk-jobs per 256-thread block; 64 float4-lanes (1 wave) each.
    const int job  = blockIdx.x * 4 + (threadIdx.x >> 6);
    const int lane = threadIdx.x & 63;
    const int b    = job >> 6;            // / NCHUNK
    const int k    = job & (NCHUNK - 1);  // % NCHUNK
    const int t0   = k * L;
    const int tb   = (k == 0) ? 0 : (t0 - W);

    const f4* __restrict__ xp = (const f4*)x + ((size_t)b * T + tb) * ROWF4 + lane;
    f4* __restrict__ op       = (f4*)out     + ((size_t)b * T + tb) * ROWF4 + lane;

    if (k == 0) {
        run_rows<L, 0>(xp, op);           // exact from t=0, store all 32 rows
    } else {
        run_rows<W + L, W>(xp, op);       // 24 warm-up rows, store last 32
    }
}

extern "C" void kernel_launch(void* const* d_in, const int* in_sizes, int n_in,
                              void* d_out, int out_size, void* d_ws, size_t ws_size,
                              hipStream_t stream) {
    const float* x = (const float*)d_in[0];
    float* out = (float*)d_out;
    const int n_jobs = B * NCHUNK;                 // 4096
    ema_kernel<<<dim3(n_jobs / 4), dim3(256), 0, stream>>>(x, out);
}

// Round 3
// 233.836 us; speedup vs baseline: 1.0635x; 1.0635x over previous
//
#include <hip/hip_runtime.h>

// InputDefenseLayer: clip(x, -3.5, 3.5) then EMA scan along T (axis 1):
//   s_0 = xc_0 ; s_t = 0.25*xc_t + 0.75*s_{t-1}
// x: (B=64, T=2048, C=256) float32, contiguous, C innermost.
//
// R4 changes vs R3 (R3: 97 us -- 16-row reg buffer SPILLED: VGPR=64,
// WRITE 128->182 MiB scratch amplification; but BW rose 3.0->3.37 TB/s
// despite junk traffic => store-decoupling direction confirmed):
//  - 8-row output buffer o0..o7 (32 VGPR) instead of 16 (64 VGPR):
//    spill-free. Store-ack coupling once per 8 rows instead of every row.
//  - __launch_bounds__(256, 2): grid is 4 blocks/CU = 4 waves/SIMD max
//    anyway, so the 256-VGPR budget costs nothing and removes the
//    allocator pressure that made R3 rewrite the burst structure.
//  - sched_barrier(0) fences around each store burst: pin the
//    loads-only-phase / store-burst separation so the scheduler cannot
//    re-interleave stores into the consume chain.
// Numerics identical to R1-R3: seed at t0-W, W=24 -> err 7*0.75^24 ~ 7e-3.

constexpr int B = 64;
constexpr int T = 2048;
constexpr int C = 256;
constexpr int L = 32;            // output chunk length along T
constexpr int W = 24;            // warm-up steps: 7*0.75^24 ~ 7e-3 < 7e-2
constexpr int NCHUNK = T / L;    // 64
constexpr int ROWF4 = C / 4;     // 64 float4 per t-row
constexpr int PF = 8;            // load prefetch depth

#define CLIP_LO -3.5f
#define CLIP_HI  3.5f
#define EMA_A 0.25f
#define EMA_B 0.75f

typedef float f4 __attribute__((ext_vector_type(4)));

__device__ __forceinline__ float clipf(float v) {
    return fminf(fmaxf(v, CLIP_LO), CLIP_HI);   // -> v_med3_f32
}

__device__ __forceinline__ f4 clip4(f4 v) {
    f4 r;
    r.x = clipf(v.x);
    r.y = clipf(v.y);
    r.z = clipf(v.z);
    r.w = clipf(v.w);
    return r;
}

__device__ __forceinline__ f4 ema4(f4 s, f4 v) {
    f4 r;
    r.x = fmaf(EMA_A, v.x, EMA_B * s.x);
    r.y = fmaf(EMA_A, v.y, EMA_B * s.y);
    r.z = fmaf(EMA_A, v.z, EMA_B * s.z);
    r.w = fmaf(EMA_A, v.w, EMA_B * s.w);
    return r;
}

// Consume row r from prefetch register p##j; re-issue load for row r+PF.
// No store (warm-up). All guards fold at compile time (r, N constants).
#define STEP(j, r)                                                   \
    {                                                                \
        f4 v = clip4(p##j);                                          \
        s = ((r) == 0) ? v : ema4(s, v);                             \
        if ((r) + PF < N) p##j = xp[((r) + PF) * ROWF4];             \
    }

// Same, but also latch the state into output register oo (named, static).
#define OSTEP(j, r, oo)                                              \
    {                                                                \
        f4 v = clip4(p##j);                                          \
        s = ((r) == 0) ? v : ema4(s, v);                             \
        oo = s;                                                      \
        if ((r) + PF < N) p##j = xp[((r) + PF) * ROWF4];             \
    }

// 8 warm-up rows starting at compile-time row r0.
#define G8W(r0)                                                      \
    STEP(0, (r0) + 0) STEP(1, (r0) + 1) STEP(2, (r0) + 2)            \
    STEP(3, (r0) + 3) STEP(4, (r0) + 4) STEP(5, (r0) + 5)            \
    STEP(6, (r0) + 6) STEP(7, (r0) + 7)

// 8 output rows starting at r0, latched into o0..o7 (loads-only vmcnt
// stream in this region), then a pinned back-to-back store burst.
#define G8S(r0)                                                      \
    OSTEP(0, (r0) + 0, o0) OSTEP(1, (r0) + 1, o1)                    \
    OSTEP(2, (r0) + 2, o2) OSTEP(3, (r0) + 3, o3)                    \
    OSTEP(4, (r0) + 4, o4) OSTEP(5, (r0) + 5, o5)                    \
    OSTEP(6, (r0) + 6, o6) OSTEP(7, (r0) + 7, o7)                    \
    __builtin_amdgcn_sched_barrier(0);                               \
    __builtin_nontemporal_store(o0, op + ((r0) + 0) * ROWF4);        \
    __builtin_nontemporal_store(o1, op + ((r0) + 1) * ROWF4);        \
    __builtin_nontemporal_store(o2, op + ((r0) + 2) * ROWF4);        \
    __builtin_nontemporal_store(o3, op + ((r0) + 3) * ROWF4);        \
    __builtin_nontemporal_store(o4, op + ((r0) + 4) * ROWF4);        \
    __builtin_nontemporal_store(o5, op + ((r0) + 5) * ROWF4);        \
    __builtin_nontemporal_store(o6, op + ((r0) + 6) * ROWF4);        \
    __builtin_nontemporal_store(o7, op + ((r0) + 7) * ROWF4);        \
    __builtin_amdgcn_sched_barrier(0);

// Process rows [0, N): row 0 seeds the EMA state, rows >= SKIP are stored.
template <int N, int SKIP>
__device__ __forceinline__ void run_rows(const f4* __restrict__ xp,
                                         f4* __restrict__ op) {
    f4 p0 = xp[0 * ROWF4];
    f4 p1 = xp[1 * ROWF4];
    f4 p2 = xp[2 * ROWF4];
    f4 p3 = xp[3 * ROWF4];
    f4 p4 = xp[4 * ROWF4];
    f4 p5 = xp[5 * ROWF4];
    f4 p6 = xp[6 * ROWF4];
    f4 p7 = xp[7 * ROWF4];
    f4 s = {};
    f4 o0, o1, o2, o3, o4, o5, o6, o7;

    if constexpr (SKIP == 0) {
        static_assert(N == L, "k==0 path is 32 rows");
        G8S(0)
        G8S(8)
        G8S(16)
        G8S(24)
    } else {
        static_assert(SKIP == W && N == W + L, "warm-up path is 24+32 rows");
        G8W(0)
        G8W(8)
        G8W(16)
        G8S(24)
        G8S(32)
        G8S(40)
        G8S(48)
    }
}

__global__ __launch_bounds__(256, 2) void ema_kernel(
    const float* __restrict__ x, float* __restrict__ out)
{
    // 4 chunk-jobs per 256-thread block; 64 float4-lanes (1 wave) each.
    const int job  = blockIdx.x * 4 + (threadIdx.x >> 6);
    const int lane = threadIdx.x & 63;
    const int b    = job >> 6;            // / NCHUNK
    const int k    = job & (NCHUNK - 1);  // % NCHUNK
    const int t0   = k * L;
    const int tb   = (k == 0) ? 0 : (t0 - W);

    const f4* __restrict__ xp = (const f4*)x + ((size_t)b * T + tb) * ROWF4 + lane;
    f4* __restrict__ op       = (f4*)out     + ((size_t)b * T + tb) * ROWF4 + lane;

    if (k == 0) {
        run_rows<L, 0>(xp, op);           // exact from t=0, store all 32 rows
    } else {
        run_rows<W + L, W>(xp, op);       // 24 warm-up rows, store last 32
    }
}

extern "C" void kernel_launch(void* const* d_in, const int* in_sizes, int n_in,
                              void* d_out, int out_size, void* d_ws, size_t ws_size,
                              hipStream_t stream) {
    const float* x = (const float*)d_in[0];
    float* out = (float*)d_out;
    const int n_jobs = B * NCHUNK;                 // 4096
    ema_kernel<<<dim3(n_jobs / 4), dim3(256), 0, stream>>>(x, out);
}